// Round 8
// baseline (198.846 us; speedup 1.0000x reference)
//
#include <hip/hip_runtime.h>
#include <hip/hip_bf16.h>

typedef __attribute__((ext_vector_type(8))) _Float16 hfrag;
typedef __attribute__((ext_vector_type(4))) float ffrag;
typedef __attribute__((ext_vector_type(8))) unsigned short us8;
typedef __attribute__((ext_vector_type(4))) unsigned short us4;

#define DEVINL static __device__ __forceinline__
#define MFMAH(a, b, c)  __builtin_amdgcn_mfma_f32_16x16x32_f16((a), (b), (c), 0, 0, 0)

// DPP rotate-reduce within 16-lane rows (VALU-speed, no LDS pipe).
template <int C>
DEVINL float dppmov(float x) {
    union { float f; int i; } a, b;
    a.f = x;
    b.i = __builtin_amdgcn_update_dpp(0, a.i, C, 0xf, 0xf, true);
    return b.f;
}
DEVINL float rowmax16(float v) {
    v = fmaxf(v, dppmov<0x121>(v));   // row_ror:1
    v = fmaxf(v, dppmov<0x122>(v));   // row_ror:2
    v = fmaxf(v, dppmov<0x124>(v));   // row_ror:4
    v = fmaxf(v, dppmov<0x128>(v));   // row_ror:8
    return v;
}
DEVINL float rowsum16(float v) {
    v += dppmov<0x121>(v);
    v += dppmov<0x122>(v);
    v += dppmov<0x124>(v);
    v += dppmov<0x128>(v);
    return v;
}

// async global->LDS, 16B per lane; LDS dest = wave-uniform base + lane*16
DEVINL void gload_lds16(const _Float16* g, _Float16* l) {
    __builtin_amdgcn_global_load_lds(
        (const __attribute__((address_space(1))) unsigned int*)g,
        (__attribute__((address_space(3))) unsigned int*)l, 16, 0, 0);
}

// ---------------------------------------------------------------------------
// Kernel 1: pack weights to fp16 [512][256] (rows 0-127 Wq, 128-255 Wk,
// 256-511 Wv), gather biases.
// ---------------------------------------------------------------------------
__global__ void kprep(const float* __restrict__ Wq, const float* __restrict__ Wk,
                      const float* __restrict__ Wv, const float* __restrict__ bq,
                      const float* __restrict__ bk, const float* __restrict__ bv,
                      _Float16* __restrict__ Wh, float* __restrict__ ball) {
    int t = blockIdx.x * 256 + threadIdx.x;      // 512*256 threads
    int o = t >> 8, c = t & 255;
    float v = (o < 128) ? Wq[o * 256 + c]
            : (o < 256) ? Wk[(o - 128) * 256 + c]
                        : Wv[(o - 256) * 256 + c];
    Wh[t] = (_Float16)v;
    if (c == 0) {
        ball[o] = (o < 128) ? bq[o] : (o < 256) ? bk[o - 128] : bv[o - 256];
    }
}

// ---------------------------------------------------------------------------
// Kernel 2: 1x1 conv projections via fp16 MFMA.
// Q,K written [b][n][128] fp16; V written [b][co][n] fp16 (operand swap).
// ---------------------------------------------------------------------------
__global__ __launch_bounds__(256) void kproj(const float* __restrict__ x,
                                             const _Float16* __restrict__ Wh,
                                             const float* __restrict__ ball,
                                             _Float16* __restrict__ Qb,
                                             _Float16* __restrict__ Kb,
                                             _Float16* __restrict__ Vb) {
    __shared__ _Float16 sX[64 * 256];             // [pixel][ch], XOR-swizzled, 32KB
    const int t = threadIdx.x;
    const int lane = t & 63;
    const int wv = t >> 6;
    const int l16 = lane & 15;
    const int lg = lane >> 4;
    const int b = blockIdx.x >> 6;
    const int n0 = (blockIdx.x & 63) << 6;
    const float* xb = x + (size_t)b * 256 * 4096 + n0;

    // stage x^T tile: thread = pixel p (=lane), channel group by wave
    const int p = lane;
#pragma unroll
    for (int ci = 0; ci < 8; ++ci) {
        const int c0 = ci * 32 + (wv << 3);
        __align__(16) _Float16 th[8];
#pragma unroll
        for (int j = 0; j < 8; ++j) th[j] = (_Float16)xb[(size_t)(c0 + j) * 4096 + p];
        *(us8*)&sX[p * 256 + (c0 ^ ((p & 7) << 3))] = *(const us8*)th;
    }
    __syncthreads();

    ffrag accQK[16];  // D[pixel 16*wv+..][o=16ct+l16], o in 0..255 (Q,K)
    ffrag accV[16];   // D[o=256+64*wv+16mt+..][pixel 16*c2+l16]
#pragma unroll
    for (int i = 0; i < 16; ++i) {
        accQK[i] = ffrag{0.f, 0.f, 0.f, 0.f};
        accV[i]  = ffrag{0.f, 0.f, 0.f, 0.f};
    }
    const int rowx = 16 * wv + l16;
#pragma unroll
    for (int step = 0; step < 8; ++step) {
        const int cb = step * 32 + (lg << 3);
        hfrag ax = *(const hfrag*)&sX[rowx * 256 + (cb ^ ((rowx & 7) << 3))];
#pragma unroll
        for (int ct = 0; ct < 16; ++ct) {
            const int o = ct * 16 + l16;
            hfrag bw = *(const hfrag*)&Wh[o * 256 + cb];
            accQK[ct] = MFMAH(ax, bw, accQK[ct]);
        }
        hfrag bx[4];
#pragma unroll
        for (int c2 = 0; c2 < 4; ++c2) {
            const int px = c2 * 16 + l16;
            bx[c2] = *(const hfrag*)&sX[px * 256 + (cb ^ ((px & 7) << 3))];
        }
#pragma unroll
        for (int mt = 0; mt < 4; ++mt) {
            const int o = 256 + 64 * wv + 16 * mt + l16;
            hfrag aw = *(const hfrag*)&Wh[o * 256 + cb];
#pragma unroll
            for (int c2 = 0; c2 < 4; ++c2)
                accV[mt * 4 + c2] = MFMAH(aw, bx[c2], accV[mt * 4 + c2]);
        }
    }

    // epilogue: +bias, fp16, store
#pragma unroll
    for (int ct = 0; ct < 16; ++ct) {
        const int o = ct * 16 + l16;
        const float bias = ball[o];
        _Float16* dst = (o < 128) ? Qb : Kb;
        const int oo = o & 127;
#pragma unroll
        for (int r = 0; r < 4; ++r) {
            const int px = 16 * wv + (lg << 2) + r;
            dst[((size_t)b * 4096 + n0 + px) * 128 + oo] = (_Float16)(accQK[ct][r] + bias);
        }
    }
#pragma unroll
    for (int mt = 0; mt < 4; ++mt) {
#pragma unroll
        for (int r = 0; r < 4; ++r) {
            const int o = 64 * wv + 16 * mt + (lg << 2) + r;
            const float bias = ball[256 + o];
#pragma unroll
            for (int c2 = 0; c2 < 4; ++c2) {
                const int px = c2 * 16 + l16;
                Vb[((size_t)b * 256 + o) * 4096 + n0 + px] = (_Float16)(accV[mt * 4 + c2][r] + bias);
            }
        }
    }
}

// ---------------------------------------------------------------------------
// Kernel 3: fused flash attention, fp16, KEY-SPLIT blocks + PV co-split.
// 512 blocks x 512 threads = 4 batches x 64 q-tiles(64 rows) x 2 key-halves.
// Softmax role: wave = (qg = wv&3: 16 q-rows) x (kh = wv>>2: 32 keys).
// PV role:      wave = (ch = wv&3: 64 out-chans) x (kh: 32 keys), ALL 64 q
//   -> 16 MFMA per 8 b128 reads (V dedup; block-iter LDS reads 200 -> 128).
// Per-row rescale factors broadcast via sFac + block flag (defer-max THR=8
// makes rescale rare).  Counted-vmcnt 3-barrier pipeline (+lgkmcnt for
// cross-wave P visibility).  ~66KB LDS -> 2 blocks/CU.
// ---------------------------------------------------------------------------
__global__ __launch_bounds__(512, 4) void kattn(const _Float16* __restrict__ Qb,
                                                const _Float16* __restrict__ Kb,
                                                const _Float16* __restrict__ Vb,
                                                _Float16* __restrict__ pO,
                                                float* __restrict__ pML) {
    __shared__ __align__(16) _Float16 smem[33792];  // 67.5 KB
    _Float16* sK = smem;                        // [64][128]  16KB
    _Float16* sV = smem + 8192;                 // [256][64]  32KB
    _Float16* sP = smem + 24576;                // [64][64]    8KB
    float* sFac  = (float*)(smem + 28672);      // [2][64] rescale factors
    int* sFlag   = (int*)(smem + 28928);        // block-wide rescale flag

    const int t = threadIdx.x;
    const int lane = t & 63;
    const int wv = t >> 6;        // 0..7
    const int qg = wv & 3;        // softmax: 16-row query group (0..3)
    const int ch = wv & 3;        // PV: 64-channel slice (0..3)
    const int kh = wv >> 2;       // 32-key half (0..1), both roles
    const int l16 = lane & 15;
    const int lg = lane >> 4;

    const int blk = blockIdx.x;
    const int x8 = blk & 7;
    const int b = x8 >> 1;                          // batch per XCD pair
    const int ksel = x8 & 1;                        // key half per XCD
    const int qt4 = blk >> 3;                       // 0..63
    const int n0 = qt4 << 6;
    const int kb = ksel << 11;                      // key base (0 or 2048)

    const _Float16* Kg = Kb + (size_t)b * 4096 * 128;
    const _Float16* Vg = Vb + (size_t)b * 256 * 4096;

    // ---- Q fragments direct from global (once)
    hfrag aq[4];
    {
        const size_t gq = ((size_t)b * 4096 + n0 + 16 * qg + l16) * 128;
#pragma unroll
        for (int st = 0; st < 4; ++st)
            aq[st] = *(const hfrag*)&Qb[gq + st * 32 + lg * 8];
    }

    float m_[4], l_[4];
    ffrag O[16];    // [qt 0..3][cot 0..3]: rows qt*16+4lg+r, co ch*64+cot*16+l16
#pragma unroll
    for (int r = 0; r < 4; ++r) { m_[r] = -3e38f; l_[r] = 0.f; }
#pragma unroll
    for (int i = 0; i < 16; ++i) O[i] = ffrag{0.f, 0.f, 0.f, 0.f};

    // staging lane constants
    const int krow_in = lane >> 4;              // K: row-in-chunk (0..3)
    const int kcol = lane & 15;                 // K: col chunk index
    const int vrow_in = lane >> 3;              // V: row-in-chunk (0..7)
    const int vcol = lane & 7;                  // V: col chunk index

    for (int it = 0; it < 32; ++it) {
        const int k0 = kb + (it << 6);
        __builtin_amdgcn_s_barrier();           // everyone done reading prev tiles
        __builtin_amdgcn_sched_barrier(0);
        if (t == 0) *sFlag = 0;                 // drained by lgkmcnt before bar2
        // ---- issue K chunks (2), then V chunks (4): 6 gload_lds per wave
#pragma unroll
        for (int j = 0; j < 2; ++j) {
            const int c = 2 * wv + j;           // 0..15
            const int row = 4 * c + krow_in;
            gload_lds16(Kg + (size_t)(k0 + row) * 128 + ((kcol ^ (row & 7)) << 3),
                        sK + c * 512);
        }
        __builtin_amdgcn_sched_barrier(0);      // pin K-before-V issue order
#pragma unroll
        for (int j = 0; j < 4; ++j) {
            const int cv = 4 * wv + j;          // 0..31
            const int co = 8 * cv + vrow_in;
            gload_lds16(Vg + (size_t)co * 4096 + k0 + ((vcol ^ (co & 7)) << 3),
                        sV + cv * 512);
        }
        asm volatile("s_waitcnt vmcnt(4) lgkmcnt(0)" ::: "memory");  // K landed
        __builtin_amdgcn_s_barrier();
        __builtin_amdgcn_sched_barrier(0);

        // ---- S = Q K^T over this wave's 32 keys (8 MFMA), V loads underneath
        ffrag S[2];
        S[0] = ffrag{0.f, 0.f, 0.f, 0.f};
        S[1] = ffrag{0.f, 0.f, 0.f, 0.f};
#pragma unroll
        for (int kt = 0; kt < 2; ++kt) {
            const int rowk = kh * 32 + kt * 16 + l16;
            const int swz = (rowk & 7) << 3;
#pragma unroll
            for (int st = 0; st < 4; ++st) {
                hfrag bk = *(const hfrag*)&sK[rowk * 128 + ((st * 32 + lg * 8) ^ swz)];
                S[kt] = MFMAH(aq[st], bk, S[kt]);
            }
        }

        // ---- online softmax, defer-max THR=8 (DPP reduce over l16)
        float mx[4];
        bool grow = false;
#pragma unroll
        for (int r = 0; r < 4; ++r) {
            mx[r] = rowmax16(fmaxf(S[0][r], S[1][r]));
            grow = grow || (mx[r] > m_[r] + 8.f);
        }
        float sc[4] = {1.f, 1.f, 1.f, 1.f};
        if (__any(grow)) {                      // rare after warmup
#pragma unroll
            for (int r = 0; r < 4; ++r) {
                const float newm = fmaxf(m_[r], mx[r]);
                sc[r] = __expf(m_[r] - newm);
                m_[r] = newm;
                l_[r] *= sc[r];
            }
            if (lane == 0) *sFlag = 1;
        }
        if (l16 == 0)   // publish per-row factors (1.0 when no rescale)
            *(ffrag*)&sFac[kh * 64 + qg * 16 + 4 * lg] = ffrag{sc[0], sc[1], sc[2], sc[3]};
        float e0[4], e1[4];
#pragma unroll
        for (int r = 0; r < 4; ++r) {
            e0[r] = __expf(S[0][r] - m_[r]);    // bounded by e^8
            e1[r] = __expf(S[1][r] - m_[r]);
            l_[r] += rowsum16(e0[r] + e1[r]);
        }

        // ---- P -> LDS fp16
#pragma unroll
        for (int r = 0; r < 4; ++r) {
            const int prow = 16 * qg + 4 * lg + r;
            const int pswz = (prow & 7) << 3;
            sP[prow * 64 + ((kh * 32 + l16) ^ pswz)] = (_Float16)e0[r];
            sP[prow * 64 + ((kh * 32 + 16 + l16) ^ pswz)] = (_Float16)e1[r];
        }

        asm volatile("s_waitcnt vmcnt(0) lgkmcnt(0)" ::: "memory");  // V + P visible
        __builtin_amdgcn_s_barrier();
        __builtin_amdgcn_sched_barrier(0);

        // ---- PV role: apply broadcast rescale factors (rare)
        if (*sFlag) {
#pragma unroll
            for (int qt = 0; qt < 4; ++qt) {
                const ffrag f = *(const ffrag*)&sFac[kh * 64 + qt * 16 + 4 * lg];
#pragma unroll
                for (int cot = 0; cot < 4; ++cot)
#pragma unroll
                    for (int r = 0; r < 4; ++r)
                        O[qt * 4 + cot][r] *= f[r];
            }
        }
        // ---- O += P V : all 64 q x this wave's 64 co x 32 keys
        //      (16 MFMA per 8 b128 reads -- V fragments deduped across waves)
        hfrag pa[4];
#pragma unroll
        for (int qt = 0; qt < 4; ++qt) {
            const int prow = qt * 16 + l16;
            pa[qt] = *(const hfrag*)&sP[prow * 64 + ((kh * 32 + lg * 8) ^ ((prow & 7) << 3))];
        }
#pragma unroll
        for (int cot = 0; cot < 4; ++cot) {
            const int co = ch * 64 + cot * 16 + l16;
            const hfrag bv_ = *(const hfrag*)&sV[co * 64 + ((kh * 32 + lg * 8) ^ ((co & 7) << 3))];
#pragma unroll
            for (int qt = 0; qt < 4; ++qt)
                O[qt * 4 + cot] = MFMAH(pa[qt], bv_, O[qt * 4 + cot]);
        }
    }

    // ---- epilogue: kh merge + normalized partial out ----
    __syncthreads();
    float* sO   = (float*)smem;                 // [64][256] f32 = 64KB
    float* sml  = (float*)(smem + 32768);       // [64][2] (m,l) of kh=1
    float* sWab = (float*)(smem + 33024);       // [64][2] (wa,wc)
    if (kh == 1) {
        if (l16 == 0) {
#pragma unroll
            for (int r = 0; r < 4; ++r) {
                const int row = 16 * qg + 4 * lg + r;
                sml[row * 2] = m_[r];
                sml[row * 2 + 1] = l_[r];
            }
        }
#pragma unroll
        for (int qt = 0; qt < 4; ++qt)
#pragma unroll
            for (int cot = 0; cot < 4; ++cot)
#pragma unroll
                for (int r = 0; r < 4; ++r)
                    sO[(qt * 16 + 4 * lg + r) * 256 + ch * 64 + cot * 16 + l16] =
                        O[qt * 4 + cot][r];
    }
    __syncthreads();
    const size_t mlbase = (size_t)(ksel * 4 + b) * 4096 + n0;
    if (kh == 0) {
#pragma unroll
        for (int r = 0; r < 4; ++r) {
            const int row = 16 * qg + 4 * lg + r;
            const float pm = sml[row * 2], pl = sml[row * 2 + 1];
            const float M = fmaxf(m_[r], pm);
            const float a = __expf(m_[r] - M), c = __expf(pm - M);
            const float newl = a * l_[r] + c * pl;
            const float inv = 1.f / newl;
            if (l16 == 0) {
                sWab[row * 2] = a * inv;
                sWab[row * 2 + 1] = c * inv;
                ((float2*)pML)[mlbase + row] = make_float2(M, newl);
            }
        }
    }
    __syncthreads();
    if (kh == 0) {
#pragma unroll
        for (int qt = 0; qt < 4; ++qt) {
            float wa[4], wc[4];
#pragma unroll
            for (int r = 0; r < 4; ++r) {
                const float2 p = *(const float2*)&sWab[(qt * 16 + 4 * lg + r) * 2];
                wa[r] = p.x; wc[r] = p.y;
            }
#pragma unroll
            for (int cot = 0; cot < 4; ++cot) {
                const int co = ch * 64 + cot * 16 + l16;
#pragma unroll
                for (int r = 0; r < 4; ++r) {
                    const int row = qt * 16 + 4 * lg + r;
                    O[qt * 4 + cot][r] = wa[r] * O[qt * 4 + cot][r] +
                                         wc[r] * sO[row * 256 + co];
                }
            }
        }
    }
    __syncthreads();            // all sO reads done; safe to overlay fp16
    if (kh == 0) {
#pragma unroll
        for (int qt = 0; qt < 4; ++qt)
#pragma unroll
            for (int cot = 0; cot < 4; ++cot)
#pragma unroll
                for (int r = 0; r < 4; ++r) {
                    const int row = qt * 16 + 4 * lg + r;
                    smem[row * 256 + ch * 64 + cot * 16 + l16] =
                        (_Float16)O[qt * 4 + cot][r];
                }
    }
    __syncthreads();
    // ---- cooperative coalesced 16B store of the 32KB tile
    const size_t obase = ((size_t)(ksel * 4 + b) * 4096 + n0) * 256;
#pragma unroll
    for (int i = 0; i < 4; ++i) {
        const int idx = i * 512 + t;            // 0..2047
        const int px = idx >> 5;
        const int co8 = (idx & 31) * 8;
        *(us8*)&pO[obase + (size_t)px * 256 + co8] = *(const us8*)&smem[idx * 8];
    }
}

// ---------------------------------------------------------------------------
// Kernel 4: cross-block flash merge of the two key-halves + BN partial sums.
// 256 blocks x 256 threads; block = 64 rows.  Deterministic.
// ---------------------------------------------------------------------------
__global__ __launch_bounds__(256) void kmerge(const _Float16* __restrict__ pO,
                                              const float* __restrict__ pML,
                                              _Float16* __restrict__ wbuf,
                                              float* __restrict__ part) {
    __shared__ float sacc[2048];    // [8 rowloc][256 co]
    __shared__ float sacc2[2048];
    const int t = threadIdx.x;
    const int rowloc = t >> 5;          // 0..7
    const int co8 = (t & 31) * 8;
    float s[8], s2[8];
#pragma unroll
    for (int j = 0; j < 8; ++j) { s[j] = 0.f; s2[j] = 0.f; }
#pragma unroll 2
    for (int i = 0; i < 8; ++i) {
        const int g = blockIdx.x * 64 + i * 8 + rowloc;     // 0..16383
        const float2 ml0 = ((const float2*)pML)[g];
        const float2 ml1 = ((const float2*)pML)[16384 + g];
        const float M = fmaxf(ml0.x, ml1.x);
        const float a = __expf(ml0.x - M) * ml0.y;
        const float c = __expf(ml1.x - M) * ml1.y;
        const float inv = 1.f / (a + c);
        const float wa = a * inv, wc = c * inv;
        hfrag o0 = *(const hfrag*)&pO[(size_t)g * 256 + co8];
        hfrag o1 = *(const hfrag*)&pO[(size_t)(16384 + g) * 256 + co8];
        hfrag w;
#pragma unroll
        for (int j = 0; j < 8; ++j) {
            const float v = wa * (float)o0[j] + wc * (float)o1[j];
            w[j] = (_Float16)v;
            s[j] += v;
            s2[j] += v * v;
        }
        *(hfrag*)&wbuf[(size_t)g * 256 + co8] = w;
    }
#pragma unroll
    for (int j = 0; j < 8; ++j) {
        sacc[rowloc * 256 + co8 + j] = s[j];
        sacc2[rowloc * 256 + co8 + j] = s2[j];
    }
    __syncthreads();
    float p = 0.f, p2 = 0.f;
#pragma unroll
    for (int rl = 0; rl < 8; ++rl) {
        p  += sacc[rl * 256 + t];
        p2 += sacc2[rl * 256 + t];
    }
    part[blockIdx.x * 512 + t] = p;
    part[blockIdx.x * 512 + 256 + t] = p2;
}

// Kernel 4b: reduce partials -> stats[512]. 512 blocks x 64 lanes,
// deterministic fixed-tree shuffle reduce over 256 partial blocks.
__global__ void kstats2(const float* __restrict__ partial, float* __restrict__ stats) {
    const int ch = blockIdx.x;        // 0..511
    const int j = threadIdx.x;        // 0..63
    float s = 0.f;
#pragma unroll
    for (int i = 0; i < 4; ++i)
        s += partial[(size_t)(j + 64 * i) * 512 + ch];
    s += __shfl_xor(s, 1);
    s += __shfl_xor(s, 2);
    s += __shfl_xor(s, 4);
    s += __shfl_xor(s, 8);
    s += __shfl_xor(s, 16);
    s += __shfl_xor(s, 32);
    if (j == 0) stats[ch] = s;
}

// ---------------------------------------------------------------------------
// Kernel 5: apply BN + transpose [b][n][co] -> out[b][co][n] fp32.
// ---------------------------------------------------------------------------
__global__ __launch_bounds__(256) void kapply(const _Float16* __restrict__ w,
                                              const float* __restrict__ stats,
                                              const float* __restrict__ gamma,
                                              const float* __restrict__ beta,
                                              float* __restrict__ out) {
    __shared__ _Float16 sw[64 * 260];           // 64 rows, pad 256->260
    __shared__ float sscale[256];
    __shared__ float sshift[256];
    const int t = threadIdx.x;
    const int b = blockIdx.x >> 6;
    const int n0 = (blockIdx.x & 63) << 6;
    const _Float16* wb = w + ((size_t)b * 4096 + n0) * 256;
#pragma unroll
    for (int i = 0; i < 16; ++i) {
        const int chunk = i * 256 + t;
        const int p = chunk >> 6;
        const int cq = chunk & 63;
        *(us4*)&sw[p * 260 + cq * 4] = *(const us4*)&wb[p * 256 + cq * 4];
    }
    {
        const float mean = stats[t] * (1.f / 16384.f);
        const float var = stats[256 + t] * (1.f / 16384.f) - mean * mean;
        const float inv = rsqrtf(var + 1e-5f);
        const float sc = gamma[t] * inv;
        sscale[t] = sc;
        sshift[t] = beta[t] - mean * sc;
    }
    __syncthreads();
    const int p = t & 63;
    const int cg = t >> 6;
    float* ob = out + (size_t)b * 256 * 4096 + n0;
#pragma unroll 4
    for (int i = 0; i < 64; ++i) {
        const int co = i * 4 + cg;
        const float v = (float)sw[p * 260 + co];
        ob[(size_t)co * 4096 + p] = v * sscale[co] + sshift[co];
    }
}

// ---------------------------------------------------------------------------
extern "C" void kernel_launch(void* const* d_in, const int* in_sizes, int n_in,
                              void* d_out, int out_size, void* d_ws, size_t ws_size,
                              hipStream_t stream) {
    const float* x     = (const float*)d_in[0];
    const float* Wq    = (const float*)d_in[1];
    const float* bq    = (const float*)d_in[2];
    const float* Wk    = (const float*)d_in[3];
    const float* bk    = (const float*)d_in[4];
    const float* Wv    = (const float*)d_in[5];
    const float* bv    = (const float*)d_in[6];
    const float* gamma = (const float*)d_in[7];
    const float* beta  = (const float*)d_in[8];
    float* out = (float*)d_out;

    char* ws = (char*)d_ws;
    // lifetimes: Wh/ball [kprep->kproj]; pML aliases Wh [kattn->kmerge];
    // Qb/Kb [kproj->kattn]; wbuf aliases Qb+Kb [kmerge->kapply].
    _Float16* Wh    = (_Float16*)(ws + 0x0);        // 256 KB
    float*    pML   = (float*)(ws + 0x0);           // 256 KB (2x4x4096 float2)
    float*    ball  = (float*)(ws + 0x40000);       // 2 KB
    float*    stats = (float*)(ws + 0x40800);       // 2 KB
    float*    part  = (float*)(ws + 0x41000);       // 512 KB (256 x 512 f32)
    _Float16* Qb    = (_Float16*)(ws + 0x100000);   // 4 MB
    _Float16* Kb    = (_Float16*)(ws + 0x500000);   // 4 MB
    _Float16* wbuf  = (_Float16*)(ws + 0x100000);   // 8 MB over Qb+Kb
    _Float16* Vb    = (_Float16*)(ws + 0x900000);   // 8 MB
    _Float16* pO    = (_Float16*)(ws + 0x1100000);  // 16 MB (2x4x4096x256 fp16)
    if (ws_size < 0x2100000) return;  // 33 MB scratch (verified available)

    kprep<<<512, 256, 0, stream>>>(Wq, Wk, Wv, bq, bk, bv, Wh, ball);
    kproj<<<256, 256, 0, stream>>>(x, Wh, ball, Qb, Kb, Vb);
    kattn<<<512, 512, 0, stream>>>(Qb, Kb, Vb, pO, pML);
    kmerge<<<256, 256, 0, stream>>>(pO, pML, wbuf, part);
    kstats2<<<512, 64, 0, stream>>>(part, stats);
    kapply<<<256, 256, 0, stream>>>(wbuf, stats, gamma, beta, out);
}

// Round 11
// 143.875 us; speedup vs baseline: 1.3821x; 1.3821x over previous
//
#include <hip/hip_runtime.h>
#include <hip/hip_bf16.h>

typedef __attribute__((ext_vector_type(8))) _Float16 hfrag;
typedef __attribute__((ext_vector_type(4))) float ffrag;
typedef __attribute__((ext_vector_type(8))) unsigned short us8;
typedef __attribute__((ext_vector_type(4))) unsigned short us4;

#define DEVINL static __device__ __forceinline__
#define MFMAH(a, b, c)  __builtin_amdgcn_mfma_f32_16x16x32_f16((a), (b), (c), 0, 0, 0)

// async global->LDS, 16B per lane; LDS dest = wave-uniform base + lane*16
DEVINL void gload_lds16(const _Float16* g, _Float16* l) {
    __builtin_amdgcn_global_load_lds(
        (const __attribute__((address_space(1))) unsigned int*)g,
        (__attribute__((address_space(3))) unsigned int*)l, 16, 0, 0);
}

DEVINL int pkh(float a, float b) {       // pack 2 f32 -> fp16x2 dword
    typedef __attribute__((ext_vector_type(2))) __fp16 fp16x2;
    fp16x2 t = __builtin_amdgcn_cvt_pkrtz(a, b);
    union { fp16x2 h; int i; } u; u.h = t; return u.i;
}

// V key-permutation within 32-element groups: position m holds pixel g(m)
// where g: k4=m2, k3=m4, k2=m3 (k=pixel bits, m=storage bits).  This makes
// kattn's contiguous V-fragment load match the HW split-k mapping
// k_frag = lg*4 + (j&3) + 16*(j>>2) of mfma_16x16x32 [m162 layout].
// Inverse (pixel p -> storage m): m4=p3, m3=p2, m2=p4, m1=p1, m0=p0, m5=p5.
DEVINL int permV(int p) {
    return (p & 35) | ((p & 8) << 1) | ((p & 4) << 1) | ((p & 16) >> 2);
}

// ---------------------------------------------------------------------------
// Kernel 1: pack weights to fp16 [512][256] (rows 0-127 Wq, 128-255 Wk,
// 256-511 Wv), gather biases.
// ---------------------------------------------------------------------------
__global__ void kprep(const float* __restrict__ Wq, const float* __restrict__ Wk,
                      const float* __restrict__ Wv, const float* __restrict__ bq,
                      const float* __restrict__ bk, const float* __restrict__ bv,
                      _Float16* __restrict__ Wh, float* __restrict__ ball) {
    int t = blockIdx.x * 256 + threadIdx.x;      // 512*256 threads
    int o = t >> 8, c = t & 255;
    float v = (o < 128) ? Wq[o * 256 + c]
            : (o < 256) ? Wk[(o - 128) * 256 + c]
                        : Wv[(o - 256) * 256 + c];
    Wh[t] = (_Float16)v;
    if (c == 0) {
        ball[o] = (o < 128) ? bq[o] : (o < 256) ? bk[o - 128] : bv[o - 256];
    }
}

// ---------------------------------------------------------------------------
// Kernel 2: 1x1 conv projections via fp16 MFMA.
// Q,K written [b][n][128] fp16; V written [b][co][n] fp16 (operand swap),
// with key-index permV within 32-pixel groups (see permV).
// ---------------------------------------------------------------------------
__global__ __launch_bounds__(256) void kproj(const float* __restrict__ x,
                                             const _Float16* __restrict__ Wh,
                                             const float* __restrict__ ball,
                                             _Float16* __restrict__ Qb,
                                             _Float16* __restrict__ Kb,
                                             _Float16* __restrict__ Vb) {
    __shared__ _Float16 sX[64 * 256];             // [pixel][ch], XOR-swizzled, 32KB
    const int t = threadIdx.x;
    const int lane = t & 63;
    const int wv = t >> 6;
    const int l16 = lane & 15;
    const int lg = lane >> 4;
    const int b = blockIdx.x >> 6;
    const int n0 = (blockIdx.x & 63) << 6;
    const float* xb = x + (size_t)b * 256 * 4096 + n0;

    // stage x^T tile: thread = pixel p (=lane), channel group by wave
    const int p = lane;
#pragma unroll
    for (int ci = 0; ci < 8; ++ci) {
        const int c0 = ci * 32 + (wv << 3);
        __align__(16) _Float16 th[8];
#pragma unroll
        for (int j = 0; j < 8; ++j) th[j] = (_Float16)xb[(size_t)(c0 + j) * 4096 + p];
        *(us8*)&sX[p * 256 + (c0 ^ ((p & 7) << 3))] = *(const us8*)th;
    }
    __syncthreads();

    ffrag accQK[16];  // D[pixel 16*wv+..][o=16ct+l16], o in 0..255 (Q,K)
    ffrag accV[16];   // D[o=256+64*wv+16mt+..][pixel 16*c2+l16]
#pragma unroll
    for (int i = 0; i < 16; ++i) {
        accQK[i] = ffrag{0.f, 0.f, 0.f, 0.f};
        accV[i]  = ffrag{0.f, 0.f, 0.f, 0.f};
    }
    const int rowx = 16 * wv + l16;
#pragma unroll
    for (int step = 0; step < 8; ++step) {
        const int cb = step * 32 + (lg << 3);
        hfrag ax = *(const hfrag*)&sX[rowx * 256 + (cb ^ ((rowx & 7) << 3))];
#pragma unroll
        for (int ct = 0; ct < 16; ++ct) {
            const int o = ct * 16 + l16;
            hfrag bw = *(const hfrag*)&Wh[o * 256 + cb];
            accQK[ct] = MFMAH(ax, bw, accQK[ct]);
        }
        hfrag bx[4];
#pragma unroll
        for (int c2 = 0; c2 < 4; ++c2) {
            const int px = c2 * 16 + l16;
            bx[c2] = *(const hfrag*)&sX[px * 256 + (cb ^ ((px & 7) << 3))];
        }
#pragma unroll
        for (int mt = 0; mt < 4; ++mt) {
            const int o = 256 + 64 * wv + 16 * mt + l16;
            hfrag aw = *(const hfrag*)&Wh[o * 256 + cb];
#pragma unroll
            for (int c2 = 0; c2 < 4; ++c2)
                accV[mt * 4 + c2] = MFMAH(aw, bx[c2], accV[mt * 4 + c2]);
        }
    }

    // epilogue: +bias, fp16, store
#pragma unroll
    for (int ct = 0; ct < 16; ++ct) {
        const int o = ct * 16 + l16;
        const float bias = ball[o];
        _Float16* dst = (o < 128) ? Qb : Kb;
        const int oo = o & 127;
#pragma unroll
        for (int r = 0; r < 4; ++r) {
            const int px = 16 * wv + (lg << 2) + r;
            dst[((size_t)b * 4096 + n0 + px) * 128 + oo] = (_Float16)(accQK[ct][r] + bias);
        }
    }
#pragma unroll
    for (int mt = 0; mt < 4; ++mt) {
#pragma unroll
        for (int r = 0; r < 4; ++r) {
            const int o = 64 * wv + 16 * mt + (lg << 2) + r;
            const float bias = ball[256 + o];
#pragma unroll
            for (int c2 = 0; c2 < 4; ++c2) {
                const int px = c2 * 16 + l16;
                Vb[((size_t)b * 256 + o) * 4096 + n0 + permV(px)] =
                    (_Float16)(accV[mt * 4 + c2][r] + bias);
            }
        }
    }
}

// ---------------------------------------------------------------------------
// Kernel 3: fused flash attention, fp16, KEY-SPLIT blocks, SWAPPED QK^T.
// 512 blocks x 512 threads = 4 batches x 64 q-tiles(64 rows) x 2 key-halves.
// 8 waves = 4 q-groups(16 rows) x 2 key-halves(32 keys).  S^T = mfma(K, Q):
// lane owns ONE q-row (q=l16) and 8 P-values (2 kt x 4 r) -> softmax is
// 8 local ops + 2 shfl_xor; P packs LANE-LOCALLY (split-k B-frag mapping
// k = lg*4 + (j&3) + 16*(j>>2), m162): pb = {e0[0..3], e1[0..3]} as 4 dwords.
// V pre-permuted (permV) so contiguous b128 V reads give correct A-frags.
// PV: O^T += mfma(A=V, B=P).  Counted-vmcnt 3-barrier pipeline.  48.5KB LDS.
// kh-merge via fp16 LDS overlay; pO/pML contract identical to round 7.
// ---------------------------------------------------------------------------
__global__ __launch_bounds__(512, 4) void kattn(const _Float16* __restrict__ Qb,
                                                const _Float16* __restrict__ Kb,
                                                const _Float16* __restrict__ Vb,
                                                _Float16* __restrict__ pO,
                                                float* __restrict__ pML) {
    __shared__ __align__(16) _Float16 smem[24832];  // 48.5 KB
    _Float16* sK = smem;              // [64][128]  16KB
    _Float16* sV = smem + 8192;       // [256][64]  32KB
    float* sml = (float*)(smem + 24576);  // [64] float2 (512B)

    const int t = threadIdx.x;
    const int lane = t & 63;
    const int wv = t >> 6;        // 0..7
    const int qg = wv & 3;        // 16-row query group (0..3)
    const int kh = wv >> 2;       // 32-key half (0..1)
    const int l16 = lane & 15;
    const int lg = lane >> 4;

    const int blk = blockIdx.x;
    const int x8 = blk & 7;
    const int b = x8 >> 1;                          // batch per XCD pair
    const int ksel = x8 & 1;                        // key half per XCD
    const int qt4 = blk >> 3;                       // 0..63
    const int n0 = qt4 << 6;
    const int kb = ksel << 11;                      // key base (0 or 2048)

    const _Float16* Kg = Kb + (size_t)b * 4096 * 128;
    const _Float16* Vg = Vb + (size_t)b * 256 * 4096;

    // ---- Q fragments direct from global (once); used as MFMA B-operand
    hfrag aq[4];
    {
        const size_t gq = ((size_t)b * 4096 + n0 + 16 * qg + l16) * 128;
#pragma unroll
        for (int st = 0; st < 4; ++st)
            aq[st] = *(const hfrag*)&Qb[gq + st * 32 + lg * 8];
    }

    float m_ = -3e38f, l_ = 0.f;      // per-lane: q = 16*qg + l16
    ffrag O[16];    // O^T[co = ct*16 + lg*4 + r][q = l16]
#pragma unroll
    for (int i = 0; i < 16; ++i) O[i] = ffrag{0.f, 0.f, 0.f, 0.f};

    // staging lane constants
    const int krow_in = lane >> 4;              // K: row-in-chunk (0..3)
    const int kcol = lane & 15;                 // K: col chunk index
    const int vrow_in = lane >> 3;              // V: row-in-chunk (0..7)
    const int vcol = lane & 7;                  // V: col chunk index

    for (int it = 0; it < 32; ++it) {
        const int k0 = kb + (it << 6);
        __builtin_amdgcn_s_barrier();           // everyone done reading prev tiles
        __builtin_amdgcn_sched_barrier(0);
        // ---- issue K chunks (2), then V chunks (4): 6 gload_lds per wave
#pragma unroll
        for (int j = 0; j < 2; ++j) {
            const int c = 2 * wv + j;           // 0..15
            const int row = 4 * c + krow_in;
            gload_lds16(Kg + (size_t)(k0 + row) * 128 + ((kcol ^ (row & 7)) << 3),
                        sK + c * 512);
        }
        __builtin_amdgcn_sched_barrier(0);      // pin K-before-V issue order
#pragma unroll
        for (int j = 0; j < 4; ++j) {
            const int cv = 4 * wv + j;          // 0..31
            const int co = 8 * cv + vrow_in;
            gload_lds16(Vg + (size_t)co * 4096 + k0 + ((vcol ^ (co & 7)) << 3),
                        sV + cv * 512);
        }
        asm volatile("s_waitcnt vmcnt(4)" ::: "memory");   // K landed (V in flight)
        __builtin_amdgcn_s_barrier();
        __builtin_amdgcn_sched_barrier(0);

        // ---- S^T = K Q^T over this wave's 32 keys (8 MFMA), V loads under
        //      D[k_local = lg*4+r (tile kt)][q = l16]
        ffrag S[2];
        S[0] = ffrag{0.f, 0.f, 0.f, 0.f};
        S[1] = ffrag{0.f, 0.f, 0.f, 0.f};
#pragma unroll
        for (int kt = 0; kt < 2; ++kt) {
            const int rowk = kh * 32 + kt * 16 + l16;
            const int swz = (rowk & 7) << 3;
#pragma unroll
            for (int st = 0; st < 4; ++st) {
                hfrag ak = *(const hfrag*)&sK[rowk * 128 + ((st * 32 + lg * 8) ^ swz)];
                S[kt] = MFMAH(ak, aq[st], S[kt]);
            }
        }

        // ---- online softmax: lane-local over 8 values + 2 shfl_xor
        float mx = fmaxf(fmaxf(fmaxf(S[0][0], S[0][1]), fmaxf(S[0][2], S[0][3])),
                         fmaxf(fmaxf(S[1][0], S[1][1]), fmaxf(S[1][2], S[1][3])));
        mx = fmaxf(mx, __shfl_xor(mx, 16));
        mx = fmaxf(mx, __shfl_xor(mx, 32));
        if (__any(mx > m_ + 8.f)) {             // defer-max THR=8, rare
            const float newm = fmaxf(m_, mx);
            const float sc = __expf(m_ - newm);
            m_ = newm;
            l_ *= sc;
#pragma unroll
            for (int i = 0; i < 16; ++i)
#pragma unroll
                for (int r = 0; r < 4; ++r) O[i][r] *= sc;
        }
        float e0[4], e1[4];
        float rs = 0.f;
#pragma unroll
        for (int r = 0; r < 4; ++r) {
            e0[r] = __expf(S[0][r] - m_);       // bounded by e^8
            e1[r] = __expf(S[1][r] - m_);
            rs += e0[r] + e1[r];
        }
        rs += __shfl_xor(rs, 16);
        rs += __shfl_xor(rs, 32);
        l_ += rs;

        // ---- pack P into PV B-fragment: LANE-LOCAL under split-k mapping.
        // B-frag element j -> k = lg*4 + (j&3) + 16*(j>>2); lane holds
        // exactly keys {lg*4+r} (e0) and {16+lg*4+r} (e1).  No shuffles.
        hfrag pb;
        {
            union { int i[4]; hfrag h; } u;
            u.i[0] = pkh(e0[0], e0[1]);
            u.i[1] = pkh(e0[2], e0[3]);
            u.i[2] = pkh(e1[0], e1[1]);
            u.i[3] = pkh(e1[2], e1[3]);
            pb = u.h;
        }

        asm volatile("s_waitcnt vmcnt(0)" ::: "memory");   // V landed
        __builtin_amdgcn_s_barrier();
        __builtin_amdgcn_sched_barrier(0);

        // ---- O^T += V P^T over this wave's 32 keys (16 MFMA, 16 b128 reads)
#pragma unroll
        for (int ct = 0; ct < 16; ++ct) {
            const int co = ct * 16 + l16;
            hfrag av = *(const hfrag*)&sV[co * 64 + ((kh * 32 + lg * 8) ^ ((co & 7) << 3))];
            O[ct] = MFMAH(av, pb, O[ct]);
        }
    }

    // ---- epilogue: kh merge via fp16 LDS overlay, write pO/pML ----
    __syncthreads();
    _Float16* sE = smem;               // [64 row][256 col] fp16, col XOR-swizzled
    const int row = qg * 16 + l16;     // this lane's q-row
    const int rsw = (row & 7) << 3;
    if (kh == 1) {
        const float invl = 1.f / l_;
#pragma unroll
        for (int ct = 0; ct < 16; ++ct)
#pragma unroll
            for (int r = 0; r < 4; ++r) {
                const int col = ct * 16 + lg * 4 + r;
                sE[row * 256 + (col ^ rsw)] = (_Float16)(O[ct][r] * invl);
            }
        if (lg == 0) ((float2*)sml)[row] = make_float2(m_, l_);
    }
    __syncthreads();
    const size_t mlbase = (size_t)(ksel * 4 + b) * 4096 + n0;
    if (kh == 0) {
        const float2 pml = ((const float2*)sml)[row];
        const float M = fmaxf(m_, pml.x);
        const float a = __expf(m_ - M), c = __expf(pml.x - M);
        const float newl = a * l_ + c * pml.y;
        const float wa = a / newl, wb = c * pml.y / newl;
        if (lg == 0) ((float2*)pML)[mlbase + row] = make_float2(M, newl);
#pragma unroll
        for (int ct = 0; ct < 16; ++ct)
#pragma unroll
            for (int r = 0; r < 4; ++r) {
                const int col = ct * 16 + lg * 4 + r;
                const int idx = row * 256 + (col ^ rsw);
                const float o1n = (float)sE[idx];
                sE[idx] = (_Float16)(wa * O[ct][r] + wb * o1n);
            }
    }
    __syncthreads();
    // ---- cooperative coalesced 16B store of the 32KB tile (unswizzle)
    const size_t obase = ((size_t)(ksel * 4 + b) * 4096 + n0) * 256;
#pragma unroll
    for (int i = 0; i < 4; ++i) {
        const int idx = i * 512 + t;            // 0..2047
        const int px = idx >> 5;
        const int cg = idx & 31;                // col-group of 8
        *(us8*)&pO[obase + (size_t)px * 256 + cg * 8] =
            *(const us8*)&sE[px * 256 + (cg ^ (px & 7)) * 8];
    }
}

// ---------------------------------------------------------------------------
// Kernel 4: cross-block flash merge of the two key-halves + BN partial sums.
// 256 blocks x 256 threads; block = 64 rows.  Deterministic.
// ---------------------------------------------------------------------------
__global__ __launch_bounds__(256) void kmerge(const _Float16* __restrict__ pO,
                                              const float* __restrict__ pML,
                                              _Float16* __restrict__ wbuf,
                                              float* __restrict__ part) {
    __shared__ float sacc[2048];    // [8 rowloc][256 co]
    __shared__ float sacc2[2048];
    const int t = threadIdx.x;
    const int rowloc = t >> 5;          // 0..7
    const int co8 = (t & 31) * 8;
    float s[8], s2[8];
#pragma unroll
    for (int j = 0; j < 8; ++j) { s[j] = 0.f; s2[j] = 0.f; }
#pragma unroll 2
    for (int i = 0; i < 8; ++i) {
        const int g = blockIdx.x * 64 + i * 8 + rowloc;     // 0..16383
        const float2 ml0 = ((const float2*)pML)[g];
        const float2 ml1 = ((const float2*)pML)[16384 + g];
        const float M = fmaxf(ml0.x, ml1.x);
        const float a = __expf(ml0.x - M) * ml0.y;
        const float c = __expf(ml1.x - M) * ml1.y;
        const float inv = 1.f / (a + c);
        const float wa = a * inv, wc = c * inv;
        hfrag o0 = *(const hfrag*)&pO[(size_t)g * 256 + co8];
        hfrag o1 = *(const hfrag*)&pO[(size_t)(16384 + g) * 256 + co8];
        hfrag w;
#pragma unroll
        for (int j = 0; j < 8; ++j) {
            const float v = wa * (float)o0[j] + wc * (float)o1[j];
            w[j] = (_Float16)v;
            s[j] += v;
            s2[j] += v * v;
        }
        *(hfrag*)&wbuf[(size_t)g * 256 + co8] = w;
    }
#pragma unroll
    for (int j = 0; j < 8; ++j) {
        sacc[rowloc * 256 + co8 + j] = s[j];
        sacc2[rowloc * 256 + co8 + j] = s2[j];
    }
    __syncthreads();
    float p = 0.f, p2 = 0.f;
#pragma unroll
    for (int rl = 0; rl < 8; ++rl) {
        p  += sacc[rl * 256 + t];
        p2 += sacc2[rl * 256 + t];
    }
    part[blockIdx.x * 512 + t] = p;
    part[blockIdx.x * 512 + 256 + t] = p2;
}

// Kernel 4b: reduce partials -> stats[512]. 512 blocks x 64 lanes,
// deterministic fixed-tree shuffle reduce over 256 partial blocks.
__global__ void kstats2(const float* __restrict__ partial, float* __restrict__ stats) {
    const int ch = blockIdx.x;        // 0..511
    const int j = threadIdx.x;        // 0..63
    float s = 0.f;
#pragma unroll
    for (int i = 0; i < 4; ++i)
        s += partial[(size_t)(j + 64 * i) * 512 + ch];
    s += __shfl_xor(s, 1);
    s += __shfl_xor(s, 2);
    s += __shfl_xor(s, 4);
    s += __shfl_xor(s, 8);
    s += __shfl_xor(s, 16);
    s += __shfl_xor(s, 32);
    if (j == 0) stats[ch] = s;
}

// ---------------------------------------------------------------------------
// Kernel 5: apply BN + transpose [b][n][co] -> out[b][co][n] fp32.
// ---------------------------------------------------------------------------
__global__ __launch_bounds__(256) void kapply(const _Float16* __restrict__ w,
                                              const float* __restrict__ stats,
                                              const float* __restrict__ gamma,
                                              const float* __restrict__ beta,
                                              float* __restrict__ out) {
    __shared__ _Float16 sw[64 * 260];           // 64 rows, pad 256->260
    __shared__ float sscale[256];
    __shared__ float sshift[256];
    const int t = threadIdx.x;
    const int b = blockIdx.x >> 6;
    const int n0 = (blockIdx.x & 63) << 6;
    const _Float16* wb = w + ((size_t)b * 4096 + n0) * 256;
#pragma unroll
    for (int i = 0; i < 16; ++i) {
        const int chunk = i * 256 + t;
        const int p = chunk >> 6;
        const int cq = chunk & 63;
        *(us4*)&sw[p * 260 + cq * 4] = *(const us4*)&wb[p * 256 + cq * 4];
    }
    {
        const float mean = stats[t] * (1.f / 16384.f);
        const float var = stats[256 + t] * (1.f / 16384.f) - mean * mean;
        const float inv = rsqrtf(var + 1e-5f);
        const float sc = gamma[t] * inv;
        sscale[t] = sc;
        sshift[t] = beta[t] - mean * sc;
    }
    __syncthreads();
    const int p = t & 63;
    const int cg = t >> 6;
    float* ob = out + (size_t)b * 256 * 4096 + n0;
#pragma unroll 4
    for (int i = 0; i < 64; ++i) {
        const int co = i * 4 + cg;
        const float v = (float)sw[p * 260 + co];
        ob[(size_t)co * 4096 + p] = v * sscale[co] + sshift[co];
    }
}

// ---------------------------------------------------------------------------
extern "C" void kernel_launch(void* const* d_in, const int* in_sizes, int n_in,
                              void* d_out, int out_size, void* d_ws, size_t ws_size,
                              hipStream_t stream) {
    const float* x     = (const float*)d_in[0];
    const float* Wq    = (const float*)d_in[1];
    const float* bq    = (const float*)d_in[2];
    const float* Wk    = (const float*)d_in[3];
    const float* bk    = (const float*)d_in[4];
    const float* Wv    = (const float*)d_in[5];
    const float* bv    = (const float*)d_in[6];
    const float* gamma = (const float*)d_in[7];
    const float* beta  = (const float*)d_in[8];
    float* out = (float*)d_out;

    char* ws = (char*)d_ws;
    // lifetimes: Wh/ball [kprep->kproj]; pML aliases Wh [kattn->kmerge];
    // Qb/Kb [kproj->kattn]; wbuf aliases Qb+Kb [kmerge->kapply].
    _Float16* Wh    = (_Float16*)(ws + 0x0);        // 256 KB
    float*    pML   = (float*)(ws + 0x0);           // 256 KB (2x4x4096 float2)
    float*    ball  = (float*)(ws + 0x40000);       // 2 KB
    float*    stats = (float*)(ws + 0x40800);       // 2 KB
    float*    part  = (float*)(ws + 0x41000);       // 512 KB (256 x 512 f32)
    _Float16* Qb    = (_Float16*)(ws + 0x100000);   // 4 MB
    _Float16* Kb    = (_Float16*)(ws + 0x500000);   // 4 MB
    _Float16* wbuf  = (_Float16*)(ws + 0x100000);   // 8 MB over Qb+Kb
    _Float16* Vb    = (_Float16*)(ws + 0x900000);   // 8 MB
    _Float16* pO    = (_Float16*)(ws + 0x1100000);  // 16 MB (2x4x4096x256 fp16)
    if (ws_size < 0x2100000) return;  // 33 MB scratch (verified available)

    kprep<<<512, 256, 0, stream>>>(Wq, Wk, Wv, bq, bk, bv, Wh, ball);
    kproj<<<256, 256, 0, stream>>>(x, Wh, ball, Qb, Kb, Vb);
    kattn<<<512, 512, 0, stream>>>(Qb, Kb, Vb, pO, pML);
    kmerge<<<256, 256, 0, stream>>>(pO, pML, wbuf, part);
    kstats2<<<512, 64, 0, stream>>>(part, stats);
    kapply<<<256, 256, 0, stream>>>(wbuf, stats, gamma, beta, out);
}